// Round 16
// baseline (158.609 us; speedup 1.0000x reference)
//
#include <hip/hip_runtime.h>
#include <hip/hip_bf16.h>

// GAT layer, N=8192 Fin=256 Fout=64.
// v15 = v14 with compressor row-stride fixed: adj row = 8192 ints = 2048 uint4
// (v14 used r*512 -> rows >0 read wrong data -> absmax 0.204).
//   k1c (grid 2560): blocks <512 = Wh/s1/F/G/packed A-frags;
//        blocks >=512 = ballot-compress adj -> 1-bit maskT (4KB per k2-tile).
//   k2:  no adj loads; mask tile staged ->LDS; bit test (q >> (ms*8+lm)) & 1.
//        Factored exp: p = max(Ea_i*F_j, Eb_i*G_j), no transcendentals.
//        grid 2048, 4 waves, launch_bounds(256,4), pitch-38 P transpose.
//   k3:  sums 8 octant planes, divides, ELU. No atomics, no memset.

typedef __attribute__((ext_vector_type(8))) short bf16x8;
typedef __attribute__((ext_vector_type(16))) float f32x16;

#define LOG2E 1.4426950408889634f

__device__ __forceinline__ uint pk2o(float a, float b) {
    __hip_bfloat162 h = __float22bfloat162_rn(make_float2(a, b));
    union { __hip_bfloat162 b; uint u; } c; c.b = h; return c.u;
}
__device__ __forceinline__ ushort f2bf(float x) {
    union { __hip_bfloat16 b; ushort u; } c;
    c.b = __float2bfloat16(x);
    return c.u;
}
__device__ __forceinline__ float bf2f(ushort u) {
    union { ushort u; __hip_bfloat16 b; } c;
    c.u = u;
    return __bfloat162float(c.b);
}

// ---------------- kernel 1 fused: Wh/s1/F/G/pw  +  adj->bitmask ----------------
__global__ __launch_bounds__(256) void k1c(
    const float* __restrict__ h, const float* __restrict__ W,
    const float* __restrict__ a, const int* __restrict__ adj,
    float* __restrict__ s1, float* __restrict__ Fg, float* __restrict__ Gg,
    ushort* __restrict__ pw_hi, ushort* __restrict__ pw_lo,
    unsigned long long* __restrict__ maskT)
{
    __shared__ ushort whh[16][64], whl[16][64];
    const int l = threadIdx.x & 63;
    const int w = threadIdx.x >> 6;

    if (blockIdx.x >= 512) {
        // ---- compressor: block cb handles k2-block (qi,jh)'s 32x1024 tile ----
        const int cb = blockIdx.x - 512;
        const int qi = cb >> 3;
        const int jh = cb & 7;
        const int i0 = qi * 32;
        // wave w: 256-col slice; lane l: cols l*4..l*4+3 (16B coalesced)
        const uint4* ap = reinterpret_cast<const uint4*>(
            adj + (size_t)i0 * 8192 + jh * 1024 + w * 256) + l;
        unsigned long long* mout = maskT + (size_t)cb * 512 + w * 128;
#pragma unroll 4
        for (int r = 0; r < 32; ++r) {
            const uint4 v = ap[(size_t)r * 2048];   // row stride: 8192 ints = 2048 uint4
            const unsigned long long b0 = __ballot((int)v.x > 0);
            const unsigned long long b1 = __ballot((int)v.y > 0);
            const unsigned long long b2 = __ballot((int)v.z > 0);
            const unsigned long long b3 = __ballot((int)v.w > 0);
            if (l < 4) {
                unsigned long long bb = b0;
                if (l == 1) bb = b1;
                if (l == 2) bb = b2;
                if (l == 3) bb = b3;
                mout[r * 4 + l] = bb;
            }
        }
        return;
    }

    // ---- original k1: Wh = h@W, s1/F/G, packed A-frags ----
    const int b = blockIdx.x;
    const int row0 = b * 16 + w * 4;

    float acc[4] = {0.f, 0.f, 0.f, 0.f};
    for (int k = 0; k < 256; k += 4) {
        float w0 = W[(k + 0) * 64 + l];
        float w1 = W[(k + 1) * 64 + l];
        float w2 = W[(k + 2) * 64 + l];
        float w3 = W[(k + 3) * 64 + l];
#pragma unroll
        for (int r = 0; r < 4; ++r) {
            const float4 hv = *reinterpret_cast<const float4*>(&h[(row0 + r) * 256 + k]);
            acc[r] = fmaf(hv.x, w0, acc[r]);
            acc[r] = fmaf(hv.y, w1, acc[r]);
            acc[r] = fmaf(hv.z, w2, acc[r]);
            acc[r] = fmaf(hv.w, w3, acc[r]);
        }
    }
    const float a1 = a[l];
    const float a2 = a[64 + l];
#pragma unroll
    for (int r = 0; r < 4; ++r) {
        const int row = row0 + r;
        float x1 = acc[r] * a1;
        float x2 = acc[r] * a2;
#pragma unroll
        for (int m = 32; m >= 1; m >>= 1) {
            x1 += __shfl_xor(x1, m);
            x2 += __shfl_xor(x2, m);
        }
        if (l == 0) {
            s1[row] = x1;
            Fg[row] = __builtin_amdgcn_exp2f(x2 * LOG2E);          // 2^(s2*L)
            Gg[row] = __builtin_amdgcn_exp2f(0.2f * x2 * LOG2E);   // 2^(.2*s2*L)
        }
        const ushort hi = f2bf(acc[r]);
        const ushort lo = f2bf(acc[r] - bf2f(hi));
        whh[w * 4 + r][l] = hi;
        whl[w * 4 + r][l] = lo;
    }
    __syncthreads();
    // PW[jstep=b][ft][lane l] = wh[(l>>5)*8+e][ft*32+(l&31)], e=0..7
    const int ft = w & 1;
    const ushort (*src)[64] = (w < 2) ? whh : whl;
    ushort* dst = (w < 2) ? pw_hi : pw_lo;
    const int hh = l >> 5;
    union { bf16x8 v; ushort s[8]; } fr;
#pragma unroll
    for (int e = 0; e < 8; ++e)
        fr.s[e] = src[hh * 8 + e][ft * 32 + (l & 31)];
    *reinterpret_cast<bf16x8*>(&dst[(size_t)(b * 2 + ft) * 512 + l * 8]) = fr.v;
}

// ---------------- kernel 2: mask-driven fused attention ----------------

// p = max(Ea*F, Eb*G) masked by ballot bit (qword e, bit sh)
#define PGRP(G_, RS) { \
    const unsigned long long* qr_ = &mq[(w4 * 32 + 8 * (G_) + g8) * 4]; \
    const unsigned long long q0_ = qr_[0], q1_ = qr_[1], q2_ = qr_[2], q3_ = qr_[3]; \
    float p0_ = fmaxf(Ea[G_] * fv.x, Eb[G_] * gv.x); if (!((q0_ >> sh) & 1)) p0_ = 0.f; \
    float p1_ = fmaxf(Ea[G_] * fv.y, Eb[G_] * gv.y); if (!((q1_ >> sh) & 1)) p1_ = 0.f; \
    float p2_ = fmaxf(Ea[G_] * fv.z, Eb[G_] * gv.z); if (!((q2_ >> sh) & 1)) p2_ = 0.f; \
    float p3_ = fmaxf(Ea[G_] * fv.w, Eb[G_] * gv.w); if (!((q3_ >> sh) & 1)) p3_ = 0.f; \
    RS += (p0_ + p1_) + (p2_ + p3_); \
    *reinterpret_cast<uint2*>(&myp[(8 * (G_) + g8) * 38 + jc]) = \
        make_uint2(pk2o(p0_, p1_), pk2o(p2_, p3_)); \
}

__global__ __launch_bounds__(256, 4) void k2_attn(
    const unsigned long long* __restrict__ maskT,
    const float* __restrict__ s1g,
    const float* __restrict__ Fgl, const float* __restrict__ Ggl,
    const ushort* __restrict__ pw_hi, const ushort* __restrict__ pw_lo,
    float* __restrict__ pacc8, float* __restrict__ pden8)
{
    // [0,4096) F | [4096,8192) G | [8192,12288) mask tile | [12288,22016) myp
    // (4 x 2432B, pitch 38) | [22016,22528) dlds. Epilogue aliases [0,6144).
    __shared__ __align__(16) unsigned char smem[22528];

    const int t   = threadIdx.x;
    const int l   = t & 63;
    const int w4  = t >> 6;
    const int qi  = blockIdx.x >> 3;
    const int jh  = blockIdx.x & 7;
    const int i0  = qi * 32;
    const int row = l & 31;           // B-frag row (MFMA role)
    const int kh  = l >> 5;           // k-half (MFMA role)
    const int g8  = l >> 3;           // row-in-octet (P role)
    const int lm  = l & 7;            // lane-in-octet
    const int jc  = lm * 4;           // j-offset (P role)

    float*  Fl  = reinterpret_cast<float*>(smem);
    float*  Gl  = reinterpret_cast<float*>(smem + 4096);
    unsigned long long* mq = reinterpret_cast<unsigned long long*>(smem + 8192);
    ushort* myp = reinterpret_cast<ushort*>(smem + 12288) + w4 * 1216;
    float (*dlds)[32] = reinterpret_cast<float(*)[32]>(smem + 22016);

    // stage F,G octants + mask tile (all coalesced)
    reinterpret_cast<float4*>(Fl)[t] =
        reinterpret_cast<const float4*>(Fgl + jh * 1024)[t];
    reinterpret_cast<float4*>(Gl)[t] =
        reinterpret_cast<const float4*>(Ggl + jh * 1024)[t];
    reinterpret_cast<ulonglong2*>(mq)[t] =
        reinterpret_cast<const ulonglong2*>(maskT + (size_t)blockIdx.x * 512)[t];

    // per-lane row coefficients: Ea=2^((s1-m)L), Eb=2^((.2s1-m)L)
    float Ea[4], Eb[4];
#pragma unroll
    for (int g = 0; g < 4; ++g) {
        const float s1v = s1g[i0 + 8 * g + g8];
        const float mq_ = s1v + 16.0f;
        const float m   = fmaxf(mq_, 0.2f * mq_);
        Ea[g] = __builtin_amdgcn_exp2f((s1v - m) * LOG2E);
        Eb[g] = __builtin_amdgcn_exp2f(fmaf(0.2f, s1v, -m) * LOG2E);
    }
    __syncthreads();

    const int jb  = jh * 1024 + w4 * 256;
    const int js0 = jb >> 4;

    f32x16 acc0 = {0.f,0.f,0.f,0.f,0.f,0.f,0.f,0.f,0.f,0.f,0.f,0.f,0.f,0.f,0.f,0.f};
    f32x16 acc1 = {0.f,0.f,0.f,0.f,0.f,0.f,0.f,0.f,0.f,0.f,0.f,0.f,0.f,0.f,0.f,0.f};
    float rs0 = 0.f, rs1 = 0.f, rs2 = 0.f, rs3 = 0.f;

#pragma unroll
    for (int ms = 0; ms < 8; ++ms) {
        const uint sh = ms * 8 + lm;    // ballot bit index
        const float4 fv = *reinterpret_cast<const float4*>(&Fl[w4 * 256 + ms * 32 + jc]);
        const float4 gv = *reinterpret_cast<const float4*>(&Gl[w4 * 256 + ms * 32 + jc]);

        PGRP(0, rs0)
        PGRP(1, rs1)
        PGRP(2, rs2)
        PGRP(3, rs3)

#pragma unroll
        for (int ksx = 0; ksx < 2; ++ksx) {
            const int js = js0 + ms * 2 + ksx;
            const bf16x8 ah0 = *reinterpret_cast<const bf16x8*>(&pw_hi[(size_t)(js * 2 + 0) * 512 + l * 8]);
            const bf16x8 al0 = *reinterpret_cast<const bf16x8*>(&pw_lo[(size_t)(js * 2 + 0) * 512 + l * 8]);
            const bf16x8 ah1 = *reinterpret_cast<const bf16x8*>(&pw_hi[(size_t)(js * 2 + 1) * 512 + l * 8]);
            const bf16x8 al1 = *reinterpret_cast<const bf16x8*>(&pw_lo[(size_t)(js * 2 + 1) * 512 + l * 8]);
            union { bf16x8 v; ushort4 q[2]; } bh;
            bh.q[0] = *reinterpret_cast<const ushort4*>(&myp[row * 38 + ksx * 16 + kh * 8]);
            bh.q[1] = *reinterpret_cast<const ushort4*>(&myp[row * 38 + ksx * 16 + kh * 8 + 4]);
            acc0 = __builtin_amdgcn_mfma_f32_32x32x16_bf16(ah0, bh.v, acc0, 0, 0, 0);
            acc0 = __builtin_amdgcn_mfma_f32_32x32x16_bf16(al0, bh.v, acc0, 0, 0, 0);
            acc1 = __builtin_amdgcn_mfma_f32_32x32x16_bf16(ah1, bh.v, acc1, 0, 0, 0);
            acc1 = __builtin_amdgcn_mfma_f32_32x32x16_bf16(al1, bh.v, acc1, 0, 0, 0);
        }
    }

    // ---- denominators: 8-lane reduce, per-wave rows into dlds ----
#define RED8(RS) RS += __shfl_xor(RS, 1); RS += __shfl_xor(RS, 2); RS += __shfl_xor(RS, 4);
    RED8(rs0) RED8(rs1) RED8(rs2) RED8(rs3)
    if (lm == 0) {
        dlds[w4][g8]      = rs0;
        dlds[w4][8 + g8]  = rs1;
        dlds[w4][16 + g8] = rs2;
        dlds[w4][24 + g8] = rs3;
    }
    __syncthreads();   // dlds ready; retires myp/Fl/Gl/mq before aliasing

    if (w4 == 0 && l < 32)
        pden8[(size_t)jh * 8192 + i0 + l] =
            dlds[0][l] + dlds[1][l] + dlds[2][l] + dlds[3][l];

    // ---- cross-wave acc reduce in 4 chunks of 4 floats (6 KB alias) ----
    float* sldsc = reinterpret_cast<float*>(smem);   // [3][2][64][4]
#pragma unroll
    for (int c = 0; c < 4; ++c) {
        if (w4 != 0) {
            float4* d0 = reinterpret_cast<float4*>(&sldsc[(((w4 - 1) * 2 + 0) * 64 + l) * 4]);
            float4* d1 = reinterpret_cast<float4*>(&sldsc[(((w4 - 1) * 2 + 1) * 64 + l) * 4]);
            *d0 = make_float4(acc0[c*4+0], acc0[c*4+1], acc0[c*4+2], acc0[c*4+3]);
            *d1 = make_float4(acc1[c*4+0], acc1[c*4+1], acc1[c*4+2], acc1[c*4+3]);
        }
        __syncthreads();
        if (w4 == 0) {
#pragma unroll
            for (int s = 0; s < 3; ++s) {
                const float4 v0 = *reinterpret_cast<const float4*>(&sldsc[((s * 2 + 0) * 64 + l) * 4]);
                const float4 v1 = *reinterpret_cast<const float4*>(&sldsc[((s * 2 + 1) * 64 + l) * 4]);
                acc0[c*4+0] += v0.x; acc0[c*4+1] += v0.y; acc0[c*4+2] += v0.z; acc0[c*4+3] += v0.w;
                acc1[c*4+0] += v1.x; acc1[c*4+1] += v1.y; acc1[c*4+2] += v1.z; acc1[c*4+3] += v1.w;
            }
        }
        __syncthreads();
    }

    if (w4 == 0) {
        // D layout (32x32): col=l&31 -> node row; feat-in-half = j + 8g + 4kh
        float* pb = pacc8 + ((size_t)jh * 8192 + i0 + row) * 64;
#pragma unroll
        for (int g = 0; g < 4; ++g) {
            *reinterpret_cast<float4*>(pb + 8 * g + 4 * kh) =
                make_float4(acc0[g*4+0], acc0[g*4+1], acc0[g*4+2], acc0[g*4+3]);
            *reinterpret_cast<float4*>(pb + 32 + 8 * g + 4 * kh) =
                make_float4(acc1[g*4+0], acc1[g*4+1], acc1[g*4+2], acc1[g*4+3]);
        }
    }
}

// ---------------- kernel 3: sum 8 octant planes, divide, ELU ----------------
__global__ __launch_bounds__(256) void k3_fin(
    const float* __restrict__ pacc8, const float* __restrict__ pden8,
    float* __restrict__ out)
{
    const int idx = blockIdx.x * 256 + threadIdx.x;   // 131072 float4-groups
    const int row = idx >> 4;
    float den = 0.f;
    float4 v = make_float4(0.f, 0.f, 0.f, 0.f);
#pragma unroll
    for (int p = 0; p < 8; ++p) {
        den += pden8[p * 8192 + row];
        const float4 u = reinterpret_cast<const float4*>(pacc8 + (size_t)p * 524288)[idx];
        v.x += u.x; v.y += u.y; v.z += u.z; v.w += u.w;
    }
    const float inv = 1.0f / den;
    float4 o; float x;
    x = v.x * inv; o.x = (x > 0.f) ? x : expm1f(x);
    x = v.y * inv; o.y = (x > 0.f) ? x : expm1f(x);
    x = v.z * inv; o.z = (x > 0.f) ? x : expm1f(x);
    x = v.w * inv; o.w = (x > 0.f) ? x : expm1f(x);
    reinterpret_cast<float4*>(out)[idx] = o;
}

extern "C" void kernel_launch(void* const* d_in, const int* in_sizes, int n_in,
                              void* d_out, int out_size, void* d_ws, size_t ws_size,
                              hipStream_t stream) {
    const float* h   = (const float*)d_in[0];
    const int*   adj = (const int*)d_in[1];
    const float* W   = (const float*)d_in[2];
    const float* a   = (const float*)d_in[3];
    float* out = (float*)d_out;

    float*  s1    = (float*)d_ws;                  // 8192 f32
    float*  Fg    = s1 + 8192;                     // 8192 f32 = 2^(s2*L)
    float*  Gg    = Fg + 8192;                     // 8192 f32 = 2^(.2*s2*L)
    ushort* pw_hi = (ushort*)(Gg + 8192);          // 1MB packed A-frags (hi)
    ushort* pw_lo = pw_hi + 512 * 1024;            // 1MB (lo)
    unsigned long long* maskT =
        (unsigned long long*)(pw_lo + 512 * 1024); // 2048 tiles x 512 qwords = 8MB
    float*  pacc8 = (float*)(maskT + 2048 * 512);  // [8][8192][64] f32 (16MB)
    float*  pden8 = pacc8 + 8 * 8192 * 64;         // [8][8192] f32

    hipLaunchKernelGGL(k1c, dim3(2560), dim3(256), 0, stream,
                       h, W, a, adj, s1, Fg, Gg, pw_hi, pw_lo, maskT);
    hipLaunchKernelGGL(k2_attn, dim3(2048), dim3(256), 0, stream,
                       maskT, s1, Fg, Gg, pw_hi, pw_lo, pacc8, pden8);
    hipLaunchKernelGGL(k3_fin, dim3(512), dim3(256), 0, stream,
                       pacc8, pden8, out);
}

// Round 17
// 152.721 us; speedup vs baseline: 1.0386x; 1.0386x over previous
//
#include <hip/hip_runtime.h>
#include <hip/hip_bf16.h>

// GAT layer, N=8192 Fin=256 Fout=64.
// v16 = v15 with a ROW-CONTIGUOUS compressor (the discriminating experiment):
//   R16 lesson: the 268MB adj read costs ~85-90us (~3TB/s) wherever it runs.
//   All previous adj readers interleaved 32 row-streams (32KB jumps between
//   consecutive accesses). v16's compressor: wave = ONE adj row, walked
//   sequentially (32 x 1KB contiguous = clean 32KB stream, like the 7TB/s
//   fills). Same maskT layout/bit-order (qword e, bit b <-> col 4b+e).
//   If this streams at ~6TB/s -> total ~100us; if still ~3TB/s -> adj read
//   is pattern-independent and v13 was already at the roofline.
//   k2: mask-driven, factored exp, no adj loads (unchanged from v15).
//   k3: sums 8 octant planes, divides, ELU (unchanged).

typedef __attribute__((ext_vector_type(8))) short bf16x8;
typedef __attribute__((ext_vector_type(16))) float f32x16;

#define LOG2E 1.4426950408889634f

__device__ __forceinline__ uint pk2o(float a, float b) {
    __hip_bfloat162 h = __float22bfloat162_rn(make_float2(a, b));
    union { __hip_bfloat162 b; uint u; } c; c.b = h; return c.u;
}
__device__ __forceinline__ ushort f2bf(float x) {
    union { __hip_bfloat16 b; ushort u; } c;
    c.b = __float2bfloat16(x);
    return c.u;
}
__device__ __forceinline__ float bf2f(ushort u) {
    union { ushort u; __hip_bfloat16 b; } c;
    c.u = u;
    return __bfloat162float(c.b);
}

// ---------------- kernel 1 fused: Wh/s1/F/G/pw  +  adj->bitmask ----------------
__global__ __launch_bounds__(256) void k1c(
    const float* __restrict__ h, const float* __restrict__ W,
    const float* __restrict__ a, const int* __restrict__ adj,
    float* __restrict__ s1, float* __restrict__ Fg, float* __restrict__ Gg,
    ushort* __restrict__ pw_hi, ushort* __restrict__ pw_lo,
    unsigned long long* __restrict__ maskT)
{
    __shared__ ushort whh[16][64], whl[16][64];
    const int l = threadIdx.x & 63;
    const int w = threadIdx.x >> 6;

    if (blockIdx.x >= 512) {
        // ---- compressor: wave = one full adj row, sequential 32KB stream ----
        const int cb = blockIdx.x - 512;       // 0..2047
        const int rg = cb * 4 + w;             // this wave's row (0..8191)
        const int qi = rg >> 5;
        const int rt = rg & 31;                // row-in-tile
        const uint4* ap = reinterpret_cast<const uint4*>(
            adj + (size_t)rg * 8192) + l;      // lane l: 16B at col l*4
        unsigned long long* mrow = maskT + (size_t)qi * 4096 + rt * 4;
#pragma unroll 8
        for (int it = 0; it < 32; ++it) {      // col chunk it*256 .. +256
            const uint4 v = ap[it * 64];       // contiguous 1KB/wave per step
            const unsigned long long b0 = __ballot((int)v.x > 0);
            const unsigned long long b1 = __ballot((int)v.y > 0);
            const unsigned long long b2 = __ballot((int)v.z > 0);
            const unsigned long long b3 = __ballot((int)v.w > 0);
            if (l < 4) {
                unsigned long long bb = b0;
                if (l == 1) bb = b1;
                if (l == 2) bb = b2;
                if (l == 3) bb = b3;
                // tile (qi, jh=it>>2), slice w4s=it&3, qword e=l
                mrow[(it >> 2) * 512 + (it & 3) * 128 + l] = bb;
            }
        }
        return;
    }

    // ---- original k1: Wh = h@W, s1/F/G, packed A-frags ----
    const int b = blockIdx.x;
    const int row0 = b * 16 + w * 4;

    float acc[4] = {0.f, 0.f, 0.f, 0.f};
    for (int k = 0; k < 256; k += 4) {
        float w0 = W[(k + 0) * 64 + l];
        float w1 = W[(k + 1) * 64 + l];
        float w2 = W[(k + 2) * 64 + l];
        float w3 = W[(k + 3) * 64 + l];
#pragma unroll
        for (int r = 0; r < 4; ++r) {
            const float4 hv = *reinterpret_cast<const float4*>(&h[(row0 + r) * 256 + k]);
            acc[r] = fmaf(hv.x, w0, acc[r]);
            acc[r] = fmaf(hv.y, w1, acc[r]);
            acc[r] = fmaf(hv.z, w2, acc[r]);
            acc[r] = fmaf(hv.w, w3, acc[r]);
        }
    }
    const float a1 = a[l];
    const float a2 = a[64 + l];
#pragma unroll
    for (int r = 0; r < 4; ++r) {
        const int row = row0 + r;
        float x1 = acc[r] * a1;
        float x2 = acc[r] * a2;
#pragma unroll
        for (int m = 32; m >= 1; m >>= 1) {
            x1 += __shfl_xor(x1, m);
            x2 += __shfl_xor(x2, m);
        }
        if (l == 0) {
            s1[row] = x1;
            Fg[row] = __builtin_amdgcn_exp2f(x2 * LOG2E);          // 2^(s2*L)
            Gg[row] = __builtin_amdgcn_exp2f(0.2f * x2 * LOG2E);   // 2^(.2*s2*L)
        }
        const ushort hi = f2bf(acc[r]);
        const ushort lo = f2bf(acc[r] - bf2f(hi));
        whh[w * 4 + r][l] = hi;
        whl[w * 4 + r][l] = lo;
    }
    __syncthreads();
    // PW[jstep=b][ft][lane l] = wh[(l>>5)*8+e][ft*32+(l&31)], e=0..7
    const int ft = w & 1;
    const ushort (*src)[64] = (w < 2) ? whh : whl;
    ushort* dst = (w < 2) ? pw_hi : pw_lo;
    const int hh = l >> 5;
    union { bf16x8 v; ushort s[8]; } fr;
#pragma unroll
    for (int e = 0; e < 8; ++e)
        fr.s[e] = src[hh * 8 + e][ft * 32 + (l & 31)];
    *reinterpret_cast<bf16x8*>(&dst[(size_t)(b * 2 + ft) * 512 + l * 8]) = fr.v;
}

// ---------------- kernel 2: mask-driven fused attention ----------------

// p = max(Ea*F, Eb*G) masked by ballot bit (qword e, bit sh)
#define PGRP(G_, RS) { \
    const unsigned long long* qr_ = &mq[(w4 * 32 + 8 * (G_) + g8) * 4]; \
    const unsigned long long q0_ = qr_[0], q1_ = qr_[1], q2_ = qr_[2], q3_ = qr_[3]; \
    float p0_ = fmaxf(Ea[G_] * fv.x, Eb[G_] * gv.x); if (!((q0_ >> sh) & 1)) p0_ = 0.f; \
    float p1_ = fmaxf(Ea[G_] * fv.y, Eb[G_] * gv.y); if (!((q1_ >> sh) & 1)) p1_ = 0.f; \
    float p2_ = fmaxf(Ea[G_] * fv.z, Eb[G_] * gv.z); if (!((q2_ >> sh) & 1)) p2_ = 0.f; \
    float p3_ = fmaxf(Ea[G_] * fv.w, Eb[G_] * gv.w); if (!((q3_ >> sh) & 1)) p3_ = 0.f; \
    RS += (p0_ + p1_) + (p2_ + p3_); \
    *reinterpret_cast<uint2*>(&myp[(8 * (G_) + g8) * 38 + jc]) = \
        make_uint2(pk2o(p0_, p1_), pk2o(p2_, p3_)); \
}

__global__ __launch_bounds__(256, 4) void k2_attn(
    const unsigned long long* __restrict__ maskT,
    const float* __restrict__ s1g,
    const float* __restrict__ Fgl, const float* __restrict__ Ggl,
    const ushort* __restrict__ pw_hi, const ushort* __restrict__ pw_lo,
    float* __restrict__ pacc8, float* __restrict__ pden8)
{
    // [0,4096) F | [4096,8192) G | [8192,12288) mask tile | [12288,22016) myp
    // (4 x 2432B, pitch 38) | [22016,22528) dlds. Epilogue aliases [0,6144).
    __shared__ __align__(16) unsigned char smem[22528];

    const int t   = threadIdx.x;
    const int l   = t & 63;
    const int w4  = t >> 6;
    const int qi  = blockIdx.x >> 3;
    const int jh  = blockIdx.x & 7;
    const int i0  = qi * 32;
    const int row = l & 31;           // B-frag row (MFMA role)
    const int kh  = l >> 5;           // k-half (MFMA role)
    const int g8  = l >> 3;           // row-in-octet (P role)
    const int lm  = l & 7;            // lane-in-octet
    const int jc  = lm * 4;           // j-offset (P role)

    float*  Fl  = reinterpret_cast<float*>(smem);
    float*  Gl  = reinterpret_cast<float*>(smem + 4096);
    unsigned long long* mq = reinterpret_cast<unsigned long long*>(smem + 8192);
    ushort* myp = reinterpret_cast<ushort*>(smem + 12288) + w4 * 1216;
    float (*dlds)[32] = reinterpret_cast<float(*)[32]>(smem + 22016);

    // stage F,G octants + mask tile (all coalesced)
    reinterpret_cast<float4*>(Fl)[t] =
        reinterpret_cast<const float4*>(Fgl + jh * 1024)[t];
    reinterpret_cast<float4*>(Gl)[t] =
        reinterpret_cast<const float4*>(Ggl + jh * 1024)[t];
    reinterpret_cast<ulonglong2*>(mq)[t] =
        reinterpret_cast<const ulonglong2*>(maskT + (size_t)blockIdx.x * 512)[t];

    // per-lane row coefficients: Ea=2^((s1-m)L), Eb=2^((.2s1-m)L)
    float Ea[4], Eb[4];
#pragma unroll
    for (int g = 0; g < 4; ++g) {
        const float s1v = s1g[i0 + 8 * g + g8];
        const float mq_ = s1v + 16.0f;
        const float m   = fmaxf(mq_, 0.2f * mq_);
        Ea[g] = __builtin_amdgcn_exp2f((s1v - m) * LOG2E);
        Eb[g] = __builtin_amdgcn_exp2f(fmaf(0.2f, s1v, -m) * LOG2E);
    }
    __syncthreads();

    const int jb  = jh * 1024 + w4 * 256;
    const int js0 = jb >> 4;

    f32x16 acc0 = {0.f,0.f,0.f,0.f,0.f,0.f,0.f,0.f,0.f,0.f,0.f,0.f,0.f,0.f,0.f,0.f};
    f32x16 acc1 = {0.f,0.f,0.f,0.f,0.f,0.f,0.f,0.f,0.f,0.f,0.f,0.f,0.f,0.f,0.f,0.f};
    float rs0 = 0.f, rs1 = 0.f, rs2 = 0.f, rs3 = 0.f;

#pragma unroll
    for (int ms = 0; ms < 8; ++ms) {
        const uint sh = ms * 8 + lm;    // ballot bit index
        const float4 fv = *reinterpret_cast<const float4*>(&Fl[w4 * 256 + ms * 32 + jc]);
        const float4 gv = *reinterpret_cast<const float4*>(&Gl[w4 * 256 + ms * 32 + jc]);

        PGRP(0, rs0)
        PGRP(1, rs1)
        PGRP(2, rs2)
        PGRP(3, rs3)

#pragma unroll
        for (int ksx = 0; ksx < 2; ++ksx) {
            const int js = js0 + ms * 2 + ksx;
            const bf16x8 ah0 = *reinterpret_cast<const bf16x8*>(&pw_hi[(size_t)(js * 2 + 0) * 512 + l * 8]);
            const bf16x8 al0 = *reinterpret_cast<const bf16x8*>(&pw_lo[(size_t)(js * 2 + 0) * 512 + l * 8]);
            const bf16x8 ah1 = *reinterpret_cast<const bf16x8*>(&pw_hi[(size_t)(js * 2 + 1) * 512 + l * 8]);
            const bf16x8 al1 = *reinterpret_cast<const bf16x8*>(&pw_lo[(size_t)(js * 2 + 1) * 512 + l * 8]);
            union { bf16x8 v; ushort4 q[2]; } bh;
            bh.q[0] = *reinterpret_cast<const ushort4*>(&myp[row * 38 + ksx * 16 + kh * 8]);
            bh.q[1] = *reinterpret_cast<const ushort4*>(&myp[row * 38 + ksx * 16 + kh * 8 + 4]);
            acc0 = __builtin_amdgcn_mfma_f32_32x32x16_bf16(ah0, bh.v, acc0, 0, 0, 0);
            acc0 = __builtin_amdgcn_mfma_f32_32x32x16_bf16(al0, bh.v, acc0, 0, 0, 0);
            acc1 = __builtin_amdgcn_mfma_f32_32x32x16_bf16(ah1, bh.v, acc1, 0, 0, 0);
            acc1 = __builtin_amdgcn_mfma_f32_32x32x16_bf16(al1, bh.v, acc1, 0, 0, 0);
        }
    }

    // ---- denominators: 8-lane reduce, per-wave rows into dlds ----
#define RED8(RS) RS += __shfl_xor(RS, 1); RS += __shfl_xor(RS, 2); RS += __shfl_xor(RS, 4);
    RED8(rs0) RED8(rs1) RED8(rs2) RED8(rs3)
    if (lm == 0) {
        dlds[w4][g8]      = rs0;
        dlds[w4][8 + g8]  = rs1;
        dlds[w4][16 + g8] = rs2;
        dlds[w4][24 + g8] = rs3;
    }
    __syncthreads();   // dlds ready; retires myp/Fl/Gl/mq before aliasing

    if (w4 == 0 && l < 32)
        pden8[(size_t)jh * 8192 + i0 + l] =
            dlds[0][l] + dlds[1][l] + dlds[2][l] + dlds[3][l];

    // ---- cross-wave acc reduce in 4 chunks of 4 floats (6 KB alias) ----
    float* sldsc = reinterpret_cast<float*>(smem);   // [3][2][64][4]
#pragma unroll
    for (int c = 0; c < 4; ++c) {
        if (w4 != 0) {
            float4* d0 = reinterpret_cast<float4*>(&sldsc[(((w4 - 1) * 2 + 0) * 64 + l) * 4]);
            float4* d1 = reinterpret_cast<float4*>(&sldsc[(((w4 - 1) * 2 + 1) * 64 + l) * 4]);
            *d0 = make_float4(acc0[c*4+0], acc0[c*4+1], acc0[c*4+2], acc0[c*4+3]);
            *d1 = make_float4(acc1[c*4+0], acc1[c*4+1], acc1[c*4+2], acc1[c*4+3]);
        }
        __syncthreads();
        if (w4 == 0) {
#pragma unroll
            for (int s = 0; s < 3; ++s) {
                const float4 v0 = *reinterpret_cast<const float4*>(&sldsc[((s * 2 + 0) * 64 + l) * 4]);
                const float4 v1 = *reinterpret_cast<const float4*>(&sldsc[((s * 2 + 1) * 64 + l) * 4]);
                acc0[c*4+0] += v0.x; acc0[c*4+1] += v0.y; acc0[c*4+2] += v0.z; acc0[c*4+3] += v0.w;
                acc1[c*4+0] += v1.x; acc1[c*4+1] += v1.y; acc1[c*4+2] += v1.z; acc1[c*4+3] += v1.w;
            }
        }
        __syncthreads();
    }

    if (w4 == 0) {
        // D layout (32x32): col=l&31 -> node row; feat-in-half = j + 8g + 4kh
        float* pb = pacc8 + ((size_t)jh * 8192 + i0 + row) * 64;
#pragma unroll
        for (int g = 0; g < 4; ++g) {
            *reinterpret_cast<float4*>(pb + 8 * g + 4 * kh) =
                make_float4(acc0[g*4+0], acc0[g*4+1], acc0[g*4+2], acc0[g*4+3]);
            *reinterpret_cast<float4*>(pb + 32 + 8 * g + 4 * kh) =
                make_float4(acc1[g*4+0], acc1[g*4+1], acc1[g*4+2], acc1[g*4+3]);
        }
    }
}

// ---------------- kernel 3: sum 8 octant planes, divide, ELU ----------------
__global__ __launch_bounds__(256) void k3_fin(
    const float* __restrict__ pacc8, const float* __restrict__ pden8,
    float* __restrict__ out)
{
    const int idx = blockIdx.x * 256 + threadIdx.x;   // 131072 float4-groups
    const int row = idx >> 4;
    float den = 0.f;
    float4 v = make_float4(0.f, 0.f, 0.f, 0.f);
#pragma unroll
    for (int p = 0; p < 8; ++p) {
        den += pden8[p * 8192 + row];
        const float4 u = reinterpret_cast<const float4*>(pacc8 + (size_t)p * 524288)[idx];
        v.x += u.x; v.y += u.y; v.z += u.z; v.w += u.w;
    }
    const float inv = 1.0f / den;
    float4 o; float x;
    x = v.x * inv; o.x = (x > 0.f) ? x : expm1f(x);
    x = v.y * inv; o.y = (x > 0.f) ? x : expm1f(x);
    x = v.z * inv; o.z = (x > 0.f) ? x : expm1f(x);
    x = v.w * inv; o.w = (x > 0.f) ? x : expm1f(x);
    reinterpret_cast<float4*>(out)[idx] = o;
}

extern "C" void kernel_launch(void* const* d_in, const int* in_sizes, int n_in,
                              void* d_out, int out_size, void* d_ws, size_t ws_size,
                              hipStream_t stream) {
    const float* h   = (const float*)d_in[0];
    const int*   adj = (const int*)d_in[1];
    const float* W   = (const float*)d_in[2];
    const float* a   = (const float*)d_in[3];
    float* out = (float*)d_out;

    float*  s1    = (float*)d_ws;                  // 8192 f32
    float*  Fg    = s1 + 8192;                     // 8192 f32 = 2^(s2*L)
    float*  Gg    = Fg + 8192;                     // 8192 f32 = 2^(.2*s2*L)
    ushort* pw_hi = (ushort*)(Gg + 8192);          // 1MB packed A-frags (hi)
    ushort* pw_lo = pw_hi + 512 * 1024;            // 1MB (lo)
    unsigned long long* maskT =
        (unsigned long long*)(pw_lo + 512 * 1024); // 2048 tiles x 512 qwords = 8MB
    float*  pacc8 = (float*)(maskT + 2048 * 512);  // [8][8192][64] f32 (16MB)
    float*  pden8 = pacc8 + 8 * 8192 * 64;         // [8][8192] f32

    hipLaunchKernelGGL(k1c, dim3(2560), dim3(256), 0, stream,
                       h, W, a, adj, s1, Fg, Gg, pw_hi, pw_lo, maskT);
    hipLaunchKernelGGL(k2_attn, dim3(2048), dim3(256), 0, stream,
                       maskT, s1, Fg, Gg, pw_hi, pw_lo, pacc8, pden8);
    hipLaunchKernelGGL(k3_fin, dim3(512), dim3(256), 0, stream,
                       pacc8, pden8, out);
}

// Round 18
// 106.253 us; speedup vs baseline: 1.4927x; 1.4373x over previous
//
#include <hip/hip_runtime.h>
#include <hip/hip_bf16.h>

// GAT layer, N=8192 Fin=256 Fout=64.
// v17 = v13 (101-102us winner: factored exp, coalesced adj, no compressor)
//       + NON-TEMPORAL adj loads. R17 established the adj read rate is
//       pattern-independent (~3TB/s in 5 structures incl. a pure sequential
//       streamer). Last shared attribute vs the 7TB/s fills: our 268MB
//       zero-reuse stream ALLOCATES in L2/L3 (1.05x L3 size -> tag thrash).
//       nt loads bypass allocation; adj has zero reuse so this cannot hurt.
//   k1: Wh=h@W; s1, F=2^(s2*L), G=2^(.2*s2*L); whT packed as MFMA A-frags.
//   k2: grid 2048 = (qi 0..255) x (jh 0..7); 4 waves; launch_bounds(256,4).
//       p = max(Ea_i*F_j, Eb_i*G_j) (no transcendentals); pitch-38 transpose.
//   k3: sums 8 octant planes, divides, ELU. No atomics, no memset.

typedef __attribute__((ext_vector_type(8))) short bf16x8;
typedef __attribute__((ext_vector_type(16))) float f32x16;
typedef __attribute__((ext_vector_type(4))) int i32x4;

#define LOG2E 1.4426950408889634f

__device__ __forceinline__ uint pk2o(float a, float b) {
    __hip_bfloat162 h = __float22bfloat162_rn(make_float2(a, b));
    union { __hip_bfloat162 b; uint u; } c; c.b = h; return c.u;
}
__device__ __forceinline__ ushort f2bf(float x) {
    union { __hip_bfloat16 b; ushort u; } c;
    c.b = __float2bfloat16(x);
    return c.u;
}
__device__ __forceinline__ float bf2f(ushort u) {
    union { ushort u; __hip_bfloat16 b; } c;
    c.u = u;
    return __bfloat162float(c.b);
}

// ---------------- kernel 1: Wh, s1, F, G, packed A-frags ----------------
__global__ __launch_bounds__(256) void k1_wh(
    const float* __restrict__ h, const float* __restrict__ W,
    const float* __restrict__ a,
    float* __restrict__ s1, float* __restrict__ Fg, float* __restrict__ Gg,
    ushort* __restrict__ pw_hi, ushort* __restrict__ pw_lo)
{
    __shared__ ushort whh[16][64], whl[16][64];
    const int l = threadIdx.x & 63;      // lane = output feature
    const int w = threadIdx.x >> 6;
    const int b = blockIdx.x;
    const int row0 = b * 16 + w * 4;

    float acc[4] = {0.f, 0.f, 0.f, 0.f};
    for (int k = 0; k < 256; k += 4) {
        float w0 = W[(k + 0) * 64 + l];
        float w1 = W[(k + 1) * 64 + l];
        float w2 = W[(k + 2) * 64 + l];
        float w3 = W[(k + 3) * 64 + l];
#pragma unroll
        for (int r = 0; r < 4; ++r) {
            const float4 hv = *reinterpret_cast<const float4*>(&h[(row0 + r) * 256 + k]);
            acc[r] = fmaf(hv.x, w0, acc[r]);
            acc[r] = fmaf(hv.y, w1, acc[r]);
            acc[r] = fmaf(hv.z, w2, acc[r]);
            acc[r] = fmaf(hv.w, w3, acc[r]);
        }
    }
    const float a1 = a[l];
    const float a2 = a[64 + l];
#pragma unroll
    for (int r = 0; r < 4; ++r) {
        const int row = row0 + r;
        float x1 = acc[r] * a1;
        float x2 = acc[r] * a2;
#pragma unroll
        for (int m = 32; m >= 1; m >>= 1) {
            x1 += __shfl_xor(x1, m);
            x2 += __shfl_xor(x2, m);
        }
        if (l == 0) {
            s1[row] = x1;
            Fg[row] = __builtin_amdgcn_exp2f(x2 * LOG2E);          // 2^(s2*L)
            Gg[row] = __builtin_amdgcn_exp2f(0.2f * x2 * LOG2E);   // 2^(.2*s2*L)
        }
        const ushort hi = f2bf(acc[r]);
        const ushort lo = f2bf(acc[r] - bf2f(hi));
        whh[w * 4 + r][l] = hi;
        whl[w * 4 + r][l] = lo;
    }
    __syncthreads();
    // PW[jstep=b][ft][lane l] = wh[(l>>5)*8+e][ft*32+(l&31)], e=0..7
    const int ft = w & 1;
    const ushort (*src)[64] = (w < 2) ? whh : whl;
    ushort* dst = (w < 2) ? pw_hi : pw_lo;
    const int hh = l >> 5;
    union { bf16x8 v; ushort s[8]; } fr;
#pragma unroll
    for (int e = 0; e < 8; ++e)
        fr.s[e] = src[hh * 8 + e][ft * 32 + (l & 31)];
    *reinterpret_cast<bf16x8*>(&dst[(size_t)(b * 2 + ft) * 512 + l * 8]) = fr.v;
}

// ---------------- kernel 2: coalesced fused attention (nt adj) ----------------

// p = max(Ea*F, Eb*G), adj-masked; fv/gv shared across the 4 row-groups
#define PGRP(G_, AV, RS) { \
    float p0_ = fmaxf(Ea[G_] * fv.x, Eb[G_] * gv.x); if ((AV).x <= 0) p0_ = 0.f; \
    float p1_ = fmaxf(Ea[G_] * fv.y, Eb[G_] * gv.y); if ((AV).y <= 0) p1_ = 0.f; \
    float p2_ = fmaxf(Ea[G_] * fv.z, Eb[G_] * gv.z); if ((AV).z <= 0) p2_ = 0.f; \
    float p3_ = fmaxf(Ea[G_] * fv.w, Eb[G_] * gv.w); if ((AV).w <= 0) p3_ = 0.f; \
    RS += (p0_ + p1_) + (p2_ + p3_); \
    *reinterpret_cast<uint2*>(&myp[(8 * (G_) + g8) * 38 + jc]) = \
        make_uint2(pk2o(p0_, p1_), pk2o(p2_, p3_)); \
}

#define NTLD(p) __builtin_nontemporal_load(reinterpret_cast<const i32x4*>(p))

__global__ __launch_bounds__(256, 4) void k2_attn(
    const int* __restrict__ adj,
    const float* __restrict__ s1g,
    const float* __restrict__ Fgl, const float* __restrict__ Ggl,
    const ushort* __restrict__ pw_hi, const ushort* __restrict__ pw_lo,
    float* __restrict__ pacc8, float* __restrict__ pden8)
{
    // [0,4096) F octant | [4096,8192) G octant | [8192,17920) myp (4 x 2432B,
    // pitch 38) | [17920,18432) dlds. Epilogue aliases [0,6144) chunked.
    __shared__ __align__(16) unsigned char smem[18432];

    const int t   = threadIdx.x;
    const int l   = t & 63;
    const int wv  = t >> 6;
    const int qi  = blockIdx.x >> 3;
    const int jh  = blockIdx.x & 7;
    const int i0  = qi * 32;
    const int row = l & 31;           // B-frag row (MFMA role)
    const int kh  = l >> 5;           // k-half (MFMA role)
    const int g8  = l >> 3;           // row-in-octet (P role)
    const int jc  = (l & 7) * 4;      // j-offset (P role)

    float*  Fl  = reinterpret_cast<float*>(smem);
    float*  Gl  = reinterpret_cast<float*>(smem + 4096);
    ushort* myp = reinterpret_cast<ushort*>(smem + 8192) + wv * 1216;
    float (*dlds)[32] = reinterpret_cast<float(*)[32]>(smem + 17920);

    // stage F,G octants (1024 floats each, coalesced)
    reinterpret_cast<float4*>(Fl)[t] =
        reinterpret_cast<const float4*>(Fgl + jh * 1024)[t];
    reinterpret_cast<float4*>(Gl)[t] =
        reinterpret_cast<const float4*>(Ggl + jh * 1024)[t];

    // per-lane row coefficients: Ea=2^((s1-m)L), Eb=2^((.2s1-m)L)
    float Ea[4], Eb[4];
#pragma unroll
    for (int g = 0; g < 4; ++g) {
        const float s1v = s1g[i0 + 8 * g + g8];
        const float mq  = s1v + 16.0f;
        const float m   = fmaxf(mq, 0.2f * mq);
        Ea[g] = __builtin_amdgcn_exp2f((s1v - m) * LOG2E);
        Eb[g] = __builtin_amdgcn_exp2f(fmaf(0.2f, s1v, -m) * LOG2E);
    }
    __syncthreads();

    const int jb  = jh * 1024 + wv * 256;
    const int js0 = jb >> 4;
    const int* ap0 = adj + (size_t)(i0 + g8) * 8192 + jb + jc;
    const int* ap1 = ap0 + (size_t)8 * 8192;
    const int* ap2 = ap0 + (size_t)16 * 8192;
    const int* ap3 = ap0 + (size_t)24 * 8192;

    f32x16 acc0 = {0.f,0.f,0.f,0.f,0.f,0.f,0.f,0.f,0.f,0.f,0.f,0.f,0.f,0.f,0.f,0.f};
    f32x16 acc1 = {0.f,0.f,0.f,0.f,0.f,0.f,0.f,0.f,0.f,0.f,0.f,0.f,0.f,0.f,0.f,0.f};
    float rs0 = 0.f, rs1 = 0.f, rs2 = 0.f, rs3 = 0.f;

    // 1-deep prefetch rotation, fully unrolled (8 ms-iters of 32 j);
    // adj loads NON-TEMPORAL (zero reuse; skip L2/L3 allocation)
    i32x4 c0 = NTLD(ap0);
    i32x4 c1 = NTLD(ap1);
    i32x4 c2 = NTLD(ap2);
    i32x4 c3 = NTLD(ap3);

#pragma unroll
    for (int ms = 0; ms < 8; ++ms) {
        const int nm = (ms < 7) ? (ms + 1) * 32 : 7 * 32;
        const i32x4 n0 = NTLD(ap0 + nm);
        const i32x4 n1 = NTLD(ap1 + nm);
        const i32x4 n2 = NTLD(ap2 + nm);
        const i32x4 n3 = NTLD(ap3 + nm);
        const float4 fv = *reinterpret_cast<const float4*>(&Fl[wv * 256 + ms * 32 + jc]);
        const float4 gv = *reinterpret_cast<const float4*>(&Gl[wv * 256 + ms * 32 + jc]);

        PGRP(0, c0, rs0)
        PGRP(1, c1, rs1)
        PGRP(2, c2, rs2)
        PGRP(3, c3, rs3)

#pragma unroll
        for (int ksx = 0; ksx < 2; ++ksx) {
            const int js = js0 + ms * 2 + ksx;
            const bf16x8 ah0 = *reinterpret_cast<const bf16x8*>(&pw_hi[(size_t)(js * 2 + 0) * 512 + l * 8]);
            const bf16x8 al0 = *reinterpret_cast<const bf16x8*>(&pw_lo[(size_t)(js * 2 + 0) * 512 + l * 8]);
            const bf16x8 ah1 = *reinterpret_cast<const bf16x8*>(&pw_hi[(size_t)(js * 2 + 1) * 512 + l * 8]);
            const bf16x8 al1 = *reinterpret_cast<const bf16x8*>(&pw_lo[(size_t)(js * 2 + 1) * 512 + l * 8]);
            union { bf16x8 v; ushort4 q[2]; } bh;
            bh.q[0] = *reinterpret_cast<const ushort4*>(&myp[row * 38 + ksx * 16 + kh * 8]);
            bh.q[1] = *reinterpret_cast<const ushort4*>(&myp[row * 38 + ksx * 16 + kh * 8 + 4]);
            acc0 = __builtin_amdgcn_mfma_f32_32x32x16_bf16(ah0, bh.v, acc0, 0, 0, 0);
            acc0 = __builtin_amdgcn_mfma_f32_32x32x16_bf16(al0, bh.v, acc0, 0, 0, 0);
            acc1 = __builtin_amdgcn_mfma_f32_32x32x16_bf16(ah1, bh.v, acc1, 0, 0, 0);
            acc1 = __builtin_amdgcn_mfma_f32_32x32x16_bf16(al1, bh.v, acc1, 0, 0, 0);
        }
        c0 = n0; c1 = n1; c2 = n2; c3 = n3;
    }

    // ---- denominators: 8-lane reduce, per-wave rows into dlds ----
#define RED8(RS) RS += __shfl_xor(RS, 1); RS += __shfl_xor(RS, 2); RS += __shfl_xor(RS, 4);
    RED8(rs0) RED8(rs1) RED8(rs2) RED8(rs3)
    if ((l & 7) == 0) {
        dlds[wv][g8]      = rs0;
        dlds[wv][8 + g8]  = rs1;
        dlds[wv][16 + g8] = rs2;
        dlds[wv][24 + g8] = rs3;
    }
    __syncthreads();   // dlds ready; also retires myp/Fl/Gl before aliasing

    if (wv == 0 && l < 32)
        pden8[(size_t)jh * 8192 + i0 + l] =
            dlds[0][l] + dlds[1][l] + dlds[2][l] + dlds[3][l];

    // ---- cross-wave acc reduce in 4 chunks of 4 floats (6 KB alias) ----
    float* sldsc = reinterpret_cast<float*>(smem);   // [3][2][64][4]
#pragma unroll
    for (int c = 0; c < 4; ++c) {
        if (wv != 0) {
            float4* d0 = reinterpret_cast<float4*>(&sldsc[(((wv - 1) * 2 + 0) * 64 + l) * 4]);
            float4* d1 = reinterpret_cast<float4*>(&sldsc[(((wv - 1) * 2 + 1) * 64 + l) * 4]);
            *d0 = make_float4(acc0[c*4+0], acc0[c*4+1], acc0[c*4+2], acc0[c*4+3]);
            *d1 = make_float4(acc1[c*4+0], acc1[c*4+1], acc1[c*4+2], acc1[c*4+3]);
        }
        __syncthreads();
        if (wv == 0) {
#pragma unroll
            for (int s = 0; s < 3; ++s) {
                const float4 v0 = *reinterpret_cast<const float4*>(&sldsc[((s * 2 + 0) * 64 + l) * 4]);
                const float4 v1 = *reinterpret_cast<const float4*>(&sldsc[((s * 2 + 1) * 64 + l) * 4]);
                acc0[c*4+0] += v0.x; acc0[c*4+1] += v0.y; acc0[c*4+2] += v0.z; acc0[c*4+3] += v0.w;
                acc1[c*4+0] += v1.x; acc1[c*4+1] += v1.y; acc1[c*4+2] += v1.z; acc1[c*4+3] += v1.w;
            }
        }
        __syncthreads();
    }

    if (wv == 0) {
        // D layout (32x32): col=l&31 -> node row; feat-in-half = j + 8g + 4kh
        float* pb = pacc8 + ((size_t)jh * 8192 + i0 + row) * 64;
#pragma unroll
        for (int g = 0; g < 4; ++g) {
            *reinterpret_cast<float4*>(pb + 8 * g + 4 * kh) =
                make_float4(acc0[g*4+0], acc0[g*4+1], acc0[g*4+2], acc0[g*4+3]);
            *reinterpret_cast<float4*>(pb + 32 + 8 * g + 4 * kh) =
                make_float4(acc1[g*4+0], acc1[g*4+1], acc1[g*4+2], acc1[g*4+3]);
        }
    }
}

// ---------------- kernel 3: sum 8 octant planes, divide, ELU ----------------
__global__ __launch_bounds__(256) void k3_fin(
    const float* __restrict__ pacc8, const float* __restrict__ pden8,
    float* __restrict__ out)
{
    const int idx = blockIdx.x * 256 + threadIdx.x;   // 131072 float4-groups
    const int row = idx >> 4;
    float den = 0.f;
    float4 v = make_float4(0.f, 0.f, 0.f, 0.f);
#pragma unroll
    for (int p = 0; p < 8; ++p) {
        den += pden8[p * 8192 + row];
        const float4 u = reinterpret_cast<const float4*>(pacc8 + (size_t)p * 524288)[idx];
        v.x += u.x; v.y += u.y; v.z += u.z; v.w += u.w;
    }
    const float inv = 1.0f / den;
    float4 o; float x;
    x = v.x * inv; o.x = (x > 0.f) ? x : expm1f(x);
    x = v.y * inv; o.y = (x > 0.f) ? x : expm1f(x);
    x = v.z * inv; o.z = (x > 0.f) ? x : expm1f(x);
    x = v.w * inv; o.w = (x > 0.f) ? x : expm1f(x);
    reinterpret_cast<float4*>(out)[idx] = o;
}

extern "C" void kernel_launch(void* const* d_in, const int* in_sizes, int n_in,
                              void* d_out, int out_size, void* d_ws, size_t ws_size,
                              hipStream_t stream) {
    const float* h   = (const float*)d_in[0];
    const int*   adj = (const int*)d_in[1];
    const float* W   = (const float*)d_in[2];
    const float* a   = (const float*)d_in[3];
    float* out = (float*)d_out;

    float*  s1    = (float*)d_ws;                  // 8192 f32
    float*  Fg    = s1 + 8192;                     // 8192 f32 = 2^(s2*L)
    float*  Gg    = Fg + 8192;                     // 8192 f32 = 2^(.2*s2*L)
    ushort* pw_hi = (ushort*)(Gg + 8192);          // 1MB packed A-frags (hi)
    ushort* pw_lo = pw_hi + 512 * 1024;            // 1MB (lo)
    float*  pacc8 = (float*)(pw_lo + 512 * 1024);  // [8][8192][64] f32 (16MB)
    float*  pden8 = pacc8 + 8 * 8192 * 64;         // [8][8192] f32

    hipLaunchKernelGGL(k1_wh, dim3(512), dim3(256), 0, stream,
                       h, W, a, s1, Fg, Gg, pw_hi, pw_lo);
    hipLaunchKernelGGL(k2_attn, dim3(2048), dim3(256), 0, stream,
                       adj, s1, Fg, Gg, pw_hi, pw_lo, pacc8, pden8);
    hipLaunchKernelGGL(k3_fin, dim3(512), dim3(256), 0, stream,
                       pacc8, pden8, out);
}

// Round 19
// 102.352 us; speedup vs baseline: 1.5496x; 1.0381x over previous
//
#include <hip/hip_runtime.h>
#include <hip/hip_bf16.h>

// GAT layer, N=8192 Fin=256 Fout=64.  FINAL (v13, R14's 102us config).
// Pipeline: k1 (Wh=h@W, s1, F=2^(s2*L), G=2^(.2s2*L), whT packed as MFMA
// A-frags hi/lo) -> k2 (fused masked softmax-numerator + P@Wh via
// mfma_32x32x16_bf16; factored exp p=max(Ea_i*F_j, Eb_i*G_j), no
// transcendentals in inner loop; adj lane<->j coalesced; P transposed via
// wave-private LDS pitch-38; per-octant partial planes, no atomics) ->
// k3 (sum 8 planes, divide, ELU).
// Roofline: k2 is bound by the unavoidable once-per-launch 268MB adj read at
// the measured pattern-independent ~3.3TB/s effective rate (6 structures
// tested R2-R18: ILP/TLP/DMA/sequential/nt all equal) => ~81us + ~20us k1/k3.

typedef __attribute__((ext_vector_type(8))) short bf16x8;
typedef __attribute__((ext_vector_type(16))) float f32x16;

#define LOG2E 1.4426950408889634f

__device__ __forceinline__ uint pk2o(float a, float b) {
    __hip_bfloat162 h = __float22bfloat162_rn(make_float2(a, b));
    union { __hip_bfloat162 b; uint u; } c; c.b = h; return c.u;
}
__device__ __forceinline__ ushort f2bf(float x) {
    union { __hip_bfloat16 b; ushort u; } c;
    c.b = __float2bfloat16(x);
    return c.u;
}
__device__ __forceinline__ float bf2f(ushort u) {
    union { ushort u; __hip_bfloat16 b; } c;
    c.u = u;
    return __bfloat162float(c.b);
}

// ---------------- kernel 1: Wh, s1, F, G, packed A-frags ----------------
__global__ __launch_bounds__(256) void k1_wh(
    const float* __restrict__ h, const float* __restrict__ W,
    const float* __restrict__ a,
    float* __restrict__ s1, float* __restrict__ Fg, float* __restrict__ Gg,
    ushort* __restrict__ pw_hi, ushort* __restrict__ pw_lo)
{
    __shared__ ushort whh[16][64], whl[16][64];
    const int l = threadIdx.x & 63;      // lane = output feature
    const int w = threadIdx.x >> 6;
    const int b = blockIdx.x;
    const int row0 = b * 16 + w * 4;

    float acc[4] = {0.f, 0.f, 0.f, 0.f};
    for (int k = 0; k < 256; k += 4) {
        float w0 = W[(k + 0) * 64 + l];
        float w1 = W[(k + 1) * 64 + l];
        float w2 = W[(k + 2) * 64 + l];
        float w3 = W[(k + 3) * 64 + l];
#pragma unroll
        for (int r = 0; r < 4; ++r) {
            const float4 hv = *reinterpret_cast<const float4*>(&h[(row0 + r) * 256 + k]);
            acc[r] = fmaf(hv.x, w0, acc[r]);
            acc[r] = fmaf(hv.y, w1, acc[r]);
            acc[r] = fmaf(hv.z, w2, acc[r]);
            acc[r] = fmaf(hv.w, w3, acc[r]);
        }
    }
    const float a1 = a[l];
    const float a2 = a[64 + l];
#pragma unroll
    for (int r = 0; r < 4; ++r) {
        const int row = row0 + r;
        float x1 = acc[r] * a1;
        float x2 = acc[r] * a2;
#pragma unroll
        for (int m = 32; m >= 1; m >>= 1) {
            x1 += __shfl_xor(x1, m);
            x2 += __shfl_xor(x2, m);
        }
        if (l == 0) {
            s1[row] = x1;
            Fg[row] = __builtin_amdgcn_exp2f(x2 * LOG2E);          // 2^(s2*L)
            Gg[row] = __builtin_amdgcn_exp2f(0.2f * x2 * LOG2E);   // 2^(.2*s2*L)
        }
        const ushort hi = f2bf(acc[r]);
        const ushort lo = f2bf(acc[r] - bf2f(hi));
        whh[w * 4 + r][l] = hi;
        whl[w * 4 + r][l] = lo;
    }
    __syncthreads();
    // PW[jstep=b][ft][lane l] = wh[(l>>5)*8+e][ft*32+(l&31)], e=0..7
    const int ft = w & 1;
    const ushort (*src)[64] = (w < 2) ? whh : whl;
    ushort* dst = (w < 2) ? pw_hi : pw_lo;
    const int hh = l >> 5;
    union { bf16x8 v; ushort s[8]; } fr;
#pragma unroll
    for (int e = 0; e < 8; ++e)
        fr.s[e] = src[hh * 8 + e][ft * 32 + (l & 31)];
    *reinterpret_cast<bf16x8*>(&dst[(size_t)(b * 2 + ft) * 512 + l * 8]) = fr.v;
}

// ---------------- kernel 2: coalesced fused attention (no-exp inner) ----------------

// p = max(Ea*F, Eb*G), adj-masked; fv/gv shared across the 4 row-groups
#define PGRP(G_, AV, RS) { \
    float p0_ = fmaxf(Ea[G_] * fv.x, Eb[G_] * gv.x); if ((AV).x <= 0) p0_ = 0.f; \
    float p1_ = fmaxf(Ea[G_] * fv.y, Eb[G_] * gv.y); if ((AV).y <= 0) p1_ = 0.f; \
    float p2_ = fmaxf(Ea[G_] * fv.z, Eb[G_] * gv.z); if ((AV).z <= 0) p2_ = 0.f; \
    float p3_ = fmaxf(Ea[G_] * fv.w, Eb[G_] * gv.w); if ((AV).w <= 0) p3_ = 0.f; \
    RS += (p0_ + p1_) + (p2_ + p3_); \
    *reinterpret_cast<uint2*>(&myp[(8 * (G_) + g8) * 38 + jc]) = \
        make_uint2(pk2o(p0_, p1_), pk2o(p2_, p3_)); \
}

__global__ __launch_bounds__(256, 4) void k2_attn(
    const int* __restrict__ adj,
    const float* __restrict__ s1g,
    const float* __restrict__ Fgl, const float* __restrict__ Ggl,
    const ushort* __restrict__ pw_hi, const ushort* __restrict__ pw_lo,
    float* __restrict__ pacc8, float* __restrict__ pden8)
{
    // [0,4096) F octant | [4096,8192) G octant | [8192,17920) myp (4 x 2432B,
    // pitch 38) | [17920,18432) dlds. Epilogue aliases [0,6144) chunked.
    __shared__ __align__(16) unsigned char smem[18432];

    const int t   = threadIdx.x;
    const int l   = t & 63;
    const int wv  = t >> 6;
    const int qi  = blockIdx.x >> 3;
    const int jh  = blockIdx.x & 7;
    const int i0  = qi * 32;
    const int row = l & 31;           // B-frag row (MFMA role)
    const int kh  = l >> 5;           // k-half (MFMA role)
    const int g8  = l >> 3;           // row-in-octet (P role)
    const int jc  = (l & 7) * 4;      // j-offset (P role)

    float*  Fl  = reinterpret_cast<float*>(smem);
    float*  Gl  = reinterpret_cast<float*>(smem + 4096);
    ushort* myp = reinterpret_cast<ushort*>(smem + 8192) + wv * 1216;
    float (*dlds)[32] = reinterpret_cast<float(*)[32]>(smem + 17920);

    // stage F,G octants (1024 floats each, coalesced)
    reinterpret_cast<float4*>(Fl)[t] =
        reinterpret_cast<const float4*>(Fgl + jh * 1024)[t];
    reinterpret_cast<float4*>(Gl)[t] =
        reinterpret_cast<const float4*>(Ggl + jh * 1024)[t];

    // per-lane row coefficients: Ea=2^((s1-m)L), Eb=2^((.2s1-m)L)
    float Ea[4], Eb[4];
#pragma unroll
    for (int g = 0; g < 4; ++g) {
        const float s1v = s1g[i0 + 8 * g + g8];
        const float mq  = s1v + 16.0f;
        const float m   = fmaxf(mq, 0.2f * mq);
        Ea[g] = __builtin_amdgcn_exp2f((s1v - m) * LOG2E);
        Eb[g] = __builtin_amdgcn_exp2f(fmaf(0.2f, s1v, -m) * LOG2E);
    }
    __syncthreads();

    const int jb  = jh * 1024 + wv * 256;
    const int js0 = jb >> 4;
    const int* ap0 = adj + (size_t)(i0 + g8) * 8192 + jb + jc;
    const int* ap1 = ap0 + (size_t)8 * 8192;
    const int* ap2 = ap0 + (size_t)16 * 8192;
    const int* ap3 = ap0 + (size_t)24 * 8192;

    f32x16 acc0 = {0.f,0.f,0.f,0.f,0.f,0.f,0.f,0.f,0.f,0.f,0.f,0.f,0.f,0.f,0.f,0.f};
    f32x16 acc1 = {0.f,0.f,0.f,0.f,0.f,0.f,0.f,0.f,0.f,0.f,0.f,0.f,0.f,0.f,0.f,0.f};
    float rs0 = 0.f, rs1 = 0.f, rs2 = 0.f, rs3 = 0.f;

    // 1-deep prefetch rotation, fully unrolled (8 ms-iters of 32 j)
    int4 c0 = *reinterpret_cast<const int4*>(ap0);
    int4 c1 = *reinterpret_cast<const int4*>(ap1);
    int4 c2 = *reinterpret_cast<const int4*>(ap2);
    int4 c3 = *reinterpret_cast<const int4*>(ap3);

#pragma unroll
    for (int ms = 0; ms < 8; ++ms) {
        const int nm = (ms < 7) ? (ms + 1) * 32 : 7 * 32;
        const int4 n0 = *reinterpret_cast<const int4*>(ap0 + nm);
        const int4 n1 = *reinterpret_cast<const int4*>(ap1 + nm);
        const int4 n2 = *reinterpret_cast<const int4*>(ap2 + nm);
        const int4 n3 = *reinterpret_cast<const int4*>(ap3 + nm);
        const float4 fv = *reinterpret_cast<const float4*>(&Fl[wv * 256 + ms * 32 + jc]);
        const float4 gv = *reinterpret_cast<const float4*>(&Gl[wv * 256 + ms * 32 + jc]);

        PGRP(0, c0, rs0)
        PGRP(1, c1, rs1)
        PGRP(2, c2, rs2)
        PGRP(3, c3, rs3)

#pragma unroll
        for (int ksx = 0; ksx < 2; ++ksx) {
            const int js = js0 + ms * 2 + ksx;
            const bf16x8 ah0 = *reinterpret_cast<const bf16x8*>(&pw_hi[(size_t)(js * 2 + 0) * 512 + l * 8]);
            const bf16x8 al0 = *reinterpret_cast<const bf16x8*>(&pw_lo[(size_t)(js * 2 + 0) * 512 + l * 8]);
            const bf16x8 ah1 = *reinterpret_cast<const bf16x8*>(&pw_hi[(size_t)(js * 2 + 1) * 512 + l * 8]);
            const bf16x8 al1 = *reinterpret_cast<const bf16x8*>(&pw_lo[(size_t)(js * 2 + 1) * 512 + l * 8]);
            union { bf16x8 v; ushort4 q[2]; } bh;
            bh.q[0] = *reinterpret_cast<const ushort4*>(&myp[row * 38 + ksx * 16 + kh * 8]);
            bh.q[1] = *reinterpret_cast<const ushort4*>(&myp[row * 38 + ksx * 16 + kh * 8 + 4]);
            acc0 = __builtin_amdgcn_mfma_f32_32x32x16_bf16(ah0, bh.v, acc0, 0, 0, 0);
            acc0 = __builtin_amdgcn_mfma_f32_32x32x16_bf16(al0, bh.v, acc0, 0, 0, 0);
            acc1 = __builtin_amdgcn_mfma_f32_32x32x16_bf16(ah1, bh.v, acc1, 0, 0, 0);
            acc1 = __builtin_amdgcn_mfma_f32_32x32x16_bf16(al1, bh.v, acc1, 0, 0, 0);
        }
        c0 = n0; c1 = n1; c2 = n2; c3 = n3;
    }

    // ---- denominators: 8-lane reduce, per-wave rows into dlds ----
#define RED8(RS) RS += __shfl_xor(RS, 1); RS += __shfl_xor(RS, 2); RS += __shfl_xor(RS, 4);
    RED8(rs0) RED8(rs1) RED8(rs2) RED8(rs3)
    if ((l & 7) == 0) {
        dlds[wv][g8]      = rs0;
        dlds[wv][8 + g8]  = rs1;
        dlds[wv][16 + g8] = rs2;
        dlds[wv][24 + g8] = rs3;
    }
    __syncthreads();   // dlds ready; also retires myp/Fl/Gl before aliasing

    if (wv == 0 && l < 32)
        pden8[(size_t)jh * 8192 + i0 + l] =
            dlds[0][l] + dlds[1][l] + dlds[2][l] + dlds[3][l];

    // ---- cross-wave acc reduce in 4 chunks of 4 floats (6 KB alias) ----
    float* sldsc = reinterpret_cast<float*>(smem);   // [3][2][64][4]
#pragma unroll
    for (int c = 0; c < 4; ++c) {
        if (wv != 0) {
            float4* d0 = reinterpret_cast<float4*>(&sldsc[(((wv - 1) * 2 + 0) * 64 + l) * 4]);
            float4* d1 = reinterpret_cast<float4*>(&sldsc[(((wv - 1) * 2 + 1) * 64 + l) * 4]);
            *d0 = make_float4(acc0[c*4+0], acc0[c*4+1], acc0[c*4+2], acc0[c*4+3]);
            *d1 = make_float4(acc1[c*4+0], acc1[c*4+1], acc1[c*4+2], acc1[c*4+3]);
        }
        __syncthreads();
        if (wv == 0) {
#pragma unroll
            for (int s = 0; s < 3; ++s) {
                const float4 v0 = *reinterpret_cast<const float4*>(&sldsc[((s * 2 + 0) * 64 + l) * 4]);
                const float4 v1 = *reinterpret_cast<const float4*>(&sldsc[((s * 2 + 1) * 64 + l) * 4]);
                acc0[c*4+0] += v0.x; acc0[c*4+1] += v0.y; acc0[c*4+2] += v0.z; acc0[c*4+3] += v0.w;
                acc1[c*4+0] += v1.x; acc1[c*4+1] += v1.y; acc1[c*4+2] += v1.z; acc1[c*4+3] += v1.w;
            }
        }
        __syncthreads();
    }

    if (wv == 0) {
        // D layout (32x32): col=l&31 -> node row; feat-in-half = j + 8g + 4kh
        float* pb = pacc8 + ((size_t)jh * 8192 + i0 + row) * 64;
#pragma unroll
        for (int g = 0; g < 4; ++g) {
            *reinterpret_cast<float4*>(pb + 8 * g + 4 * kh) =
                make_float4(acc0[g*4+0], acc0[g*4+1], acc0[g*4+2], acc0[g*4+3]);
            *reinterpret_cast<float4*>(pb + 32 + 8 * g + 4 * kh) =
                make_float4(acc1[g*4+0], acc1[g*4+1], acc1[g*4+2], acc1[g*4+3]);
        }
    }
}

// ---------------- kernel 3: sum 8 octant planes, divide, ELU ----------------
__global__ __launch_bounds__(256) void k3_fin(
    const float* __restrict__ pacc8, const float* __restrict__ pden8,
    float* __restrict__ out)
{
    const int idx = blockIdx.x * 256 + threadIdx.x;   // 131072 float4-groups
    const int row = idx >> 4;
    float den = 0.f;
    float4 v = make_float4(0.f, 0.f, 0.f, 0.f);
#pragma unroll
    for (int p = 0; p < 8; ++p) {
        den += pden8[p * 8192 + row];
        const float4 u = reinterpret_cast<const float4*>(pacc8 + (size_t)p * 524288)[idx];
        v.x += u.x; v.y += u.y; v.z += u.z; v.w += u.w;
    }
    const float inv = 1.0f / den;
    float4 o; float x;
    x = v.x * inv; o.x = (x > 0.f) ? x : expm1f(x);
    x = v.y * inv; o.y = (x > 0.f) ? x : expm1f(x);
    x = v.z * inv; o.z = (x > 0.f) ? x : expm1f(x);
    x = v.w * inv; o.w = (x > 0.f) ? x : expm1f(x);
    reinterpret_cast<float4*>(out)[idx] = o;
}

extern "C" void kernel_launch(void* const* d_in, const int* in_sizes, int n_in,
                              void* d_out, int out_size, void* d_ws, size_t ws_size,
                              hipStream_t stream) {
    const float* h   = (const float*)d_in[0];
    const int*   adj = (const int*)d_in[1];
    const float* W   = (const float*)d_in[2];
    const float* a   = (const float*)d_in[3];
    float* out = (float*)d_out;

    float*  s1    = (float*)d_ws;                  // 8192 f32
    float*  Fg    = s1 + 8192;                     // 8192 f32 = 2^(s2*L)
    float*  Gg    = Fg + 8192;                     // 8192 f32 = 2^(.2*s2*L)
    ushort* pw_hi = (ushort*)(Gg + 8192);          // 1MB packed A-frags (hi)
    ushort* pw_lo = pw_hi + 512 * 1024;            // 1MB (lo)
    float*  pacc8 = (float*)(pw_lo + 512 * 1024);  // [8][8192][64] f32 (16MB)
    float*  pden8 = pacc8 + 8 * 8192 * 64;         // [8][8192] f32

    hipLaunchKernelGGL(k1_wh, dim3(512), dim3(256), 0, stream,
                       h, W, a, s1, Fg, Gg, pw_hi, pw_lo);
    hipLaunchKernelGGL(k2_attn, dim3(2048), dim3(256), 0, stream,
                       adj, s1, Fg, Gg, pw_hi, pw_lo, pacc8, pden8);
    hipLaunchKernelGGL(k3_fin, dim3(512), dim3(256), 0, stream,
                       pacc8, pden8, out);
}